// Round 13
// baseline (419.753 us; speedup 1.0000x reference)
//
#include <hip/hip_runtime.h>

// Generalized Lotka-Volterra, RK4, D=64, batch 2048, 255 steps,
// trajectory out (batch, 256, 64) fp32.
//
// R12 post-mortem: uniform-address LDS broadcast reads cost LANE-SCALED
// return bandwidth (64x16B per b128 regardless of address sharing). R12
// delivered 8KB/feval/wave -> 2.09M fevals x 8KB / 68.8 TB/s = 249us ==
// measured. This round halves delivered bytes:
//   - lanes 0-31 read segment 0 (pairs 0-15) of the f16-packed x-vector,
//     lanes 32-63 read segment 1 (pairs 16-31): 4 ds_read_b128/feval = 4KB.
//   - each 16B is shared across wave halves by v_permlane32_swap_b32 on the
//     VALU pipe: swap(v,v) with EQUAL operands yields {seg0-bcast,
//     seg1-bcast} under either possible swap convention. The convention is
//     probed once and folded into the per-lane READ ADDRESS (pre-loop), so
//     e[] keeps static indices and the loop is convention-independent.
// LDS floor: 2048 waves x 1020 fevals x 4KB / 68.8 TB/s ~= 124us.
// VALU: ~118 cyc/feval x 2 waves/SIMD -> ~100us, hides under LDS.
//
// __launch_bounds__(256, 1): R12's VGPR_Count=36 showed the allocator
// demoted e[] to AGPRs (accvgpr_read per use = the hidden ~108 cyc/feval
// VALU inflation) even at a 256-reg budget; (256,1) gives 512 so there is
// zero pressure motive. HW occupancy stays 2 waves/SIMD (usage-based).
//
// Numerics: identical family to R5/R6/R12 (E = A + I in f16 pairs, diagonal
// -x and growth r exact fp32) — passing at absmax 3.9e-3.

constexpr int D   = 64;   // state dimension == wavefront size
constexpr int NT  = 256;  // trajectory length (255 RK4 steps)
constexpr int WPB = 4;    // waves (= batch elements) per block

typedef unsigned u32x2 __attribute__((ext_vector_type(2)));

__device__ __forceinline__ uint32_t pkrtz(float lo, float hi) {
    return __builtin_bit_cast(uint32_t, __builtin_amdgcn_cvt_pkrtz(lo, hi));
}
// DPP xor-1 on a float (quad_perm [1,0,3,2]).
__device__ __forceinline__ float dpp_xor1(float v) {
    return __int_as_float(__builtin_amdgcn_update_dpp(
        0, __float_as_int(v), 0xB1, 0xF, 0xF, true));
}
// acc += dot2(e_pair, x_pair), both operands VGPR.
__device__ __forceinline__ float dot2v(float acc, uint32_t e, uint32_t x) {
    asm("v_dot2_f32_f16 %0, %1, %2, %0" : "+v"(acc) : "v"(e), "v"(x));
    return acc;
}
// Share one reg across wave halves: returns {seg0-bcast, seg1-bcast} given
// that each half read its own segment into v (convention pre-folded into
// the read address).
__device__ __forceinline__ u32x2 plswap(uint32_t v) {
    return __builtin_amdgcn_permlane32_swap(v, v, false, false);
}

// f(xt) = xt * (r - xt + E@xt); half-split LDS broadcast + permlane share.
#define FEVAL(XT, RES)                                                        \
    do {                                                                      \
        const float xt_ = (XT);                                               \
        const uint32_t pair_ = pkrtz(xt_, dpp_xor1(xt_)); /* even lanes */    \
        wbuf[waddr] = pair_;                              /* 1 ds_write */    \
        asm volatile("s_waitcnt lgkmcnt(0)" ::: "memory");                    \
        float a0 = ri, a1 = 0.f, a2 = 0.f, a3 = 0.f;                          \
        float a4 = 0.f, a5 = 0.f, a6 = 0.f, a7 = 0.f;                         \
        _Pragma("unroll")                                                     \
        for (int j = 0; j < 4; ++j) {                     /* 4 split b128 */  \
            const uint4 v_ = *reinterpret_cast<const uint4*>(rbuf + 4 * j);   \
            const u32x2 s0_ = plswap(v_.x);                                   \
            const u32x2 s1_ = plswap(v_.y);                                   \
            const u32x2 s2_ = plswap(v_.z);                                   \
            const u32x2 s3_ = plswap(v_.w);                                   \
            a0 = dot2v(a0, e[4 * j + 0],      s0_.x);                         \
            a4 = dot2v(a4, e[16 + 4 * j + 0], s0_.y);                         \
            a1 = dot2v(a1, e[4 * j + 1],      s1_.x);                         \
            a5 = dot2v(a5, e[16 + 4 * j + 1], s1_.y);                         \
            a2 = dot2v(a2, e[4 * j + 2],      s2_.x);                         \
            a6 = dot2v(a6, e[16 + 4 * j + 2], s2_.y);                         \
            a3 = dot2v(a3, e[4 * j + 3],      s3_.x);                         \
            a7 = dot2v(a7, e[16 + 4 * j + 3], s3_.y);                         \
        }                                                                     \
        RES = xt_ * ((((a0 + a1) + (a2 + a3)) + ((a4 + a5) + (a6 + a7)))      \
                     - xt_);                                                  \
    } while (0)

__global__ __launch_bounds__(WPB * 64, 1)
void glv_rk4_kernel(const float* __restrict__ x0,
                    const float* __restrict__ r,
                    const float* __restrict__ A,
                    const float* __restrict__ tgrid,
                    float* __restrict__ out)
{
    const int lane = threadIdx.x & 63;
    const int wid  = threadIdx.x >> 6;
    const int b    = blockIdx.x * WPB + wid;   // batch element for this wave

    // Per-wave broadcast buffer: 32 pair-slots + 32 shadow (odd lanes).
    __shared__ uint32_t xf16[WPB][64];
    uint32_t* const wbuf = &xf16[wid][0];
    const int waddr = (lane >> 1) + (lane & 1) * 32;  // shadow for odd lanes

    // Probe the permlane32_swap convention ONCE; fold it into the read base
    // so that plswap(v).x is ALWAYS segment-0 data (pairs 0-15) and .y is
    // segment-1 (pairs 16-31), regardless of which half reads which.
    const uint32_t probe = (lane < 32) ? 111u : 222u;
    const u32x2 pr = __builtin_amdgcn_permlane32_swap(probe, probe, false, false);
    const bool xIsLow = (pr.x == 111u);       // wave-uniform
    const int my_base = ((lane < 32) == xIsLow) ? 0 : 16;   // word offset
    uint32_t* const rbuf = wbuf + my_base;

    // E = A + I, row `lane`, packed f16 pairs -> 32 VGPRs (one-time setup).
    uint32_t e[D / 2];
#pragma unroll
    for (int J = 0; J < D / 2; J += 2) {
        const float4 v = *reinterpret_cast<const float4*>(A + lane * D + 2 * J);
        const float e0 = v.x + ((2 * J)     == lane ? 1.0f : 0.0f);
        const float e1 = v.y + ((2 * J + 1) == lane ? 1.0f : 0.0f);
        const float e2 = v.z + ((2 * J + 2) == lane ? 1.0f : 0.0f);
        const float e3 = v.w + ((2 * J + 3) == lane ? 1.0f : 0.0f);
        e[J]     = pkrtz(e0, e1);
        e[J + 1] = pkrtz(e2, e3);
    }
    // Anti-sink fence: E loads execute exactly once, before the loop.
#pragma unroll
    for (int J = 0; J < D / 2; ++J)
        asm volatile("" : "+v"(e[J]));

    const float ri = r[lane];
    const float dt = tgrid[1] - tgrid[0];
    const float h2 = 0.5f * dt;
    const float h6 = dt * (1.0f / 6.0f);

    float x = x0[(size_t)b * D + lane];

    float* o = out + (size_t)b * NT * D + lane;
    *o = x; o += D;                            // t = 0 is x0

    for (int t = 1; t < NT; ++t) {
        float k1, k2, k3, k4;
        FEVAL(x, k1);
        FEVAL(fmaf(h2, k1, x), k2);
        FEVAL(fmaf(h2, k2, x), k3);
        FEVAL(fmaf(dt, k3, x), k4);
        x = fmaf(h6, (k1 + k4) + 2.0f * (k2 + k3), x);
        *o = x; o += D;                        // coalesced 256 B/wave store
    }
}

extern "C" void kernel_launch(void* const* d_in, const int* in_sizes, int n_in,
                              void* d_out, int out_size, void* d_ws, size_t ws_size,
                              hipStream_t stream) {
    const float* x0    = (const float*)d_in[0];
    const float* r     = (const float*)d_in[1];
    const float* A     = (const float*)d_in[2];
    const float* tgrid = (const float*)d_in[3];
    float* out         = (float*)d_out;

    const int batch = in_sizes[0] / D;          // 2048
    dim3 grid(batch / WPB);                     // 512 blocks
    dim3 block(WPB * 64);                       // 256 threads = 4 waves

    glv_rk4_kernel<<<grid, block, 0, stream>>>(x0, r, A, tgrid, out);
}

// Round 14
// 299.694 us; speedup vs baseline: 1.4006x; 1.4006x over previous
//
#include <hip/hip_runtime.h>

// Generalized Lotka-Volterra, RK4, D=64, batch 2048, 255 steps,
// trajectory out (batch, 256, 64) fp32.
//
// Structure: R6's readlane+dot2 (ZERO LDS traffic — no DS-return floor),
// with the two fixes the R2..R13 counter history demands:
//
// 1) THE PHANTOM: every round showed VGPR_Count 32-36 and 1.6-3.5x VALU
//    issue inflation -> the backend's occupancy heuristic homes e[] in
//    AGPRs (targeting 8 waves/SIMD it can never get: grid = 2048 waves =
//    2/SIMD) and inserts v_accvgpr_read per use. Fixes:
//      a) __attribute__((amdgpu_waves_per_eu(2, 2))): max=2 pins the
//         occupancy target -> ~80 VGPRs are free to use.
//      b) per-ITERATION volatile "+v" pin on all e[J] inside the time loop:
//         AGPR-homing would now cost 64 copies/iter -> VGPR residency wins.
//
// 2) SGPR-write hazards: all 32 v_readlane are batched BEFORE all 16 dot2
//    consumers (distance >= 16 -> no VALU-writes-SGPR wait states).
//
// Math (family verified R5/R6/R12: absmax 3.9e-3..5.9e-3):
//   E = A + I packed f16 pairs in 32 VGPRs; f = x .* ((r - x) + E@x);
//   diagonal & r exact fp32; E@x via v_dot2_f32_f16 (f32 accumulate),
//   broadcast operand consumed straight from SGPR ("s" constraint).
// Per feval: 1 dpp + 1 pkrtz + 32 readlane + 16 dot2 + 6 epilogue ~= 58
// VALU instr ~= 116 cyc; x 2 waves/SIMD x 1020 fevals ~= 98us VALU floor.

constexpr int D   = 64;   // state dimension == wavefront size
constexpr int NT  = 256;  // trajectory length (255 RK4 steps)
constexpr int WPB = 4;    // waves (= batch elements) per block

__device__ __forceinline__ uint32_t pkrtz(float lo, float hi) {
    return __builtin_bit_cast(uint32_t, __builtin_amdgcn_cvt_pkrtz(lo, hi));
}
// DPP xor-1 on a float (quad_perm [1,0,3,2]).
__device__ __forceinline__ float dpp_xor1(float v) {
    return __int_as_float(__builtin_amdgcn_update_dpp(
        0, __float_as_int(v), 0xB1, 0xF, 0xF, true));
}
// acc += dot2(e_pair, x_pair); e from VGPR, x_pair straight from SGPR.
#define DOT2S(ACC, E, XS) \
    asm("v_dot2_f32_f16 %0, %1, %2, %0" : "+v"(ACC) : "v"(E), "s"(XS))

// f(xt) = xt * (r - xt + E@xt); readlane broadcast, fully batched.
#define FEVAL(XT, RES)                                                        \
    do {                                                                      \
        const float xt_ = (XT);                                               \
        const uint32_t pair_ = pkrtz(xt_, dpp_xor1(xt_)); /* even lanes */    \
        uint32_t xs_[32];                                                     \
        _Pragma("unroll")                                                     \
        for (int J = 0; J < 32; ++J)                                          \
            xs_[J] = (uint32_t)__builtin_amdgcn_readlane((int)pair_, 2 * J);  \
        float a0 = ri, a1 = 0.f, a2 = 0.f, a3 = 0.f;                          \
        _Pragma("unroll")                                                     \
        for (int J = 0; J < 32; J += 4) {                                     \
            DOT2S(a0, e[J + 0], xs_[J + 0]);                                  \
            DOT2S(a1, e[J + 1], xs_[J + 1]);                                  \
            DOT2S(a2, e[J + 2], xs_[J + 2]);                                  \
            DOT2S(a3, e[J + 3], xs_[J + 3]);                                  \
        }                                                                     \
        RES = xt_ * ((((a0 + a1) + (a2 + a3))) - xt_);                        \
    } while (0)

// Per-iteration residency pin: forces e[] to live in arch VGPRs through the
// loop body (AGPR-homing would cost 64 copies per iteration).
#define PIN8(B)                                                               \
    asm volatile("" : "+v"(e[B + 0]), "+v"(e[B + 1]), "+v"(e[B + 2]),         \
                      "+v"(e[B + 3]), "+v"(e[B + 4]), "+v"(e[B + 5]),         \
                      "+v"(e[B + 6]), "+v"(e[B + 7]))

__global__ __launch_bounds__(WPB * 64)
__attribute__((amdgpu_waves_per_eu(2, 2)))
void glv_rk4_kernel(const float* __restrict__ x0,
                    const float* __restrict__ r,
                    const float* __restrict__ A,
                    const float* __restrict__ tgrid,
                    float* __restrict__ out)
{
    const int lane = threadIdx.x & 63;
    const int wid  = threadIdx.x >> 6;
    const int b    = blockIdx.x * WPB + wid;   // batch element for this wave

    // E = A + I, row `lane`, packed f16 pairs -> 32 VGPRs (one-time setup).
    uint32_t e[D / 2];
#pragma unroll
    for (int J = 0; J < D / 2; J += 2) {
        const float4 v = *reinterpret_cast<const float4*>(A + lane * D + 2 * J);
        const float e0 = v.x + ((2 * J)     == lane ? 1.0f : 0.0f);
        const float e1 = v.y + ((2 * J + 1) == lane ? 1.0f : 0.0f);
        const float e2 = v.z + ((2 * J + 2) == lane ? 1.0f : 0.0f);
        const float e3 = v.w + ((2 * J + 3) == lane ? 1.0f : 0.0f);
        e[J]     = pkrtz(e0, e1);
        e[J + 1] = pkrtz(e2, e3);
    }

    const float ri = r[lane];
    const float dt = tgrid[1] - tgrid[0];
    const float h2 = 0.5f * dt;
    const float h6 = dt * (1.0f / 6.0f);

    float x = x0[(size_t)b * D + lane];

    float* o = out + (size_t)b * NT * D + lane;
    *o = x; o += D;                            // t = 0 is x0

    for (int t = 1; t < NT; ++t) {
        PIN8(0); PIN8(8); PIN8(16); PIN8(24);  // per-iteration VGPR pin
        float k1, k2, k3, k4;
        FEVAL(x, k1);
        FEVAL(fmaf(h2, k1, x), k2);
        FEVAL(fmaf(h2, k2, x), k3);
        FEVAL(fmaf(dt, k3, x), k4);
        x = fmaf(h6, (k1 + k4) + 2.0f * (k2 + k3), x);
        *o = x; o += D;                        // coalesced 256 B/wave store
    }
}

extern "C" void kernel_launch(void* const* d_in, const int* in_sizes, int n_in,
                              void* d_out, int out_size, void* d_ws, size_t ws_size,
                              hipStream_t stream) {
    const float* x0    = (const float*)d_in[0];
    const float* r     = (const float*)d_in[1];
    const float* A     = (const float*)d_in[2];
    const float* tgrid = (const float*)d_in[3];
    float* out         = (float*)d_out;

    const int batch = in_sizes[0] / D;          // 2048
    dim3 grid(batch / WPB);                     // 512 blocks
    dim3 block(WPB * 64);                       // 256 threads = 4 waves

    glv_rk4_kernel<<<grid, block, 0, stream>>>(x0, r, A, tgrid, out);
}

// Round 15
// 292.792 us; speedup vs baseline: 1.4336x; 1.0236x over previous
//
#include <hip/hip_runtime.h>

// Generalized Lotka-Volterra, RK4, D=64, batch 2048, 255 steps,
// trajectory out (batch, 256, 64) fp32 — MFMA, zero-shuffle feedback,
// HAZARD-AMORTIZED schedule.
//
// Structure = R8 (verified, 270us): one wave / 16 batch; need-layout
// x[t][q] = X[batch p][d(t,g,q)], d = 32(t>>1)+8g+4(t&1)+q; E_perm rows so
// tile t's C-output lands exactly where the next B-fragment needs it;
// A[row=p][k=8g+j], B[k=8g+j][col=p], C[row=4g+q][col=p] (HW-verified).
//
// R11's decisive datum: an INDEPENDENT second chain overlapped nothing ->
// R8's ~1800 stall cyc/step are per-wave enforced wait-states, not hideable
// latency. Two sources, two fixes:
//  1) MFMA->VALU transition hazards (~11-18 wait states when VALU reads an
//     accumulator just written by MFMA). R8 read each tile's acc right
//     after its MFMA pair (16 transitions/step). Now: phase-split feval —
//     8 pkrtz, then 8 INDEPENDENT MFMAs back-to-back, then all elementwise
//     reads; first read is >=6 MFMA issues after its producer.
//  2) Mid-step lgkmcnt(0) for the store transpose. Now software-pipelined:
//     LDS-write x at step end, drain+read+global-store during the NEXT
//     step's k1 (feval has zero DS ops -> drain costs nothing by then).
//     DS is in-order per wave, single buffer is WAR/RAW-safe.
// Stores stay LDS-coalesced (R9: direct scattered stores = +64% WRITE_SIZE).

constexpr int D  = 64;    // state dimension
constexpr int NT = 256;   // trajectory length (255 RK4 steps)
constexpr int BW = 16;    // batch elements per wave (MFMA N)

typedef _Float16 f16x8 __attribute__((ext_vector_type(8)));
typedef float    f32x4 __attribute__((ext_vector_type(4)));

__device__ __forceinline__ uint32_t pkrtz(float lo, float hi) {
    return __builtin_bit_cast(uint32_t, __builtin_amdgcn_cvt_pkrtz(lo, hi));
}
__device__ __forceinline__ f32x4 vsplat(float v) {
    return (f32x4){v, v, v, v};
}

// f(XT) = XT .* ((r - XT) + E@XT), phase-split to amortize MFMA->VALU waits.
#define FEVAL(XT, F)                                                          \
    do {                                                                      \
        union { uint32_t u[4]; f16x8 v; } u0_, u1_;                           \
        u0_.u[0] = pkrtz(XT[0][0], XT[0][1]);                                 \
        u0_.u[1] = pkrtz(XT[0][2], XT[0][3]);                                 \
        u0_.u[2] = pkrtz(XT[1][0], XT[1][1]);                                 \
        u0_.u[3] = pkrtz(XT[1][2], XT[1][3]);                                 \
        u1_.u[0] = pkrtz(XT[2][0], XT[2][1]);                                 \
        u1_.u[1] = pkrtz(XT[2][2], XT[2][3]);                                 \
        u1_.u[2] = pkrtz(XT[3][0], XT[3][1]);                                 \
        u1_.u[3] = pkrtz(XT[3][2], XT[3][3]);                                 \
        const f16x8 bf0 = u0_.v, bf1 = u1_.v;                                 \
        f32x4 c0_[4], c1_[4];                                                 \
        _Pragma("unroll")                                                     \
        for (int t_ = 0; t_ < 4; ++t_) {                                      \
            c0_[t_] = rl[t_] - XT[t_];                                        \
            c1_[t_] = vsplat(0.0f);                                           \
        }                                                                     \
        _Pragma("unroll")                                                     \
        for (int t_ = 0; t_ < 4; ++t_) {   /* 8 independent MFMAs, batched */ \
            c0_[t_] = __builtin_amdgcn_mfma_f32_16x16x32_f16(af[t_][0], bf0, c0_[t_], 0, 0, 0); \
            c1_[t_] = __builtin_amdgcn_mfma_f32_16x16x32_f16(af[t_][1], bf1, c1_[t_], 0, 0, 0); \
        }                                                                     \
        _Pragma("unroll")                                                     \
        for (int t_ = 0; t_ < 4; ++t_)     /* reads >=6 issues downstream */  \
            F[t_] = XT[t_] * (c0_[t_] + c1_[t_]);                             \
    } while (0)

// Stage x into LDS (transposed, pad-17 rows), NO drain — flushed next step.
#define STORE_WRITE()                                                         \
    do {                                                                      \
        _Pragma("unroll")                                                     \
        for (int t_ = 0; t_ < 4; ++t_)                                        \
            _Pragma("unroll")                                                 \
            for (int q_ = 0; q_ < 4; ++q_)                                    \
                xT[(dbase[t_] + q_) * 17 + p] = x[t_][q_];                    \
    } while (0)

// Drain (writes are a full feval old), read back, coalesced global store.
#define STORE_FLUSH(TS)                                                       \
    do {                                                                      \
        asm volatile("s_waitcnt lgkmcnt(0)" ::: "memory");                    \
        _Pragma("unroll")                                                     \
        for (int i_ = 0; i_ < 16; ++i_)                                       \
            outp[(size_t)i_ * NT * D + (size_t)(TS) * D + lane] =             \
                xT[lane * 17 + i_];                                           \
    } while (0)

__global__ __launch_bounds__(64, 1)
void glv_rk4_mfma(const float* __restrict__ x0,
                  const float* __restrict__ r,
                  const float* __restrict__ A,
                  const float* __restrict__ tgrid,
                  float* __restrict__ out)
{
    const int lane = threadIdx.x & 63;
    const int g    = lane >> 4;
    const int p    = lane & 15;
    const int b0   = blockIdx.x * BW;          // first batch elem of this wave

    __shared__ float xT[D * 17];               // store-staging only

    int dbase[4];
#pragma unroll
    for (int t = 0; t < 4; ++t) dbase[t] = 32 * (t >> 1) + 8 * g + 4 * (t & 1);

    // Stationary A-fragments of permuted E (E = A + I) — HW-verified layout.
    f16x8 af[4][2];
#pragma unroll
    for (int t = 0; t < 4; ++t) {
        const int rE = 32 * (t >> 1) + 8 * (p >> 2) + 4 * (t & 1) + (p & 3);
#pragma unroll
        for (int kh = 0; kh < 2; ++kh) {
            const int c0 = 32 * kh + 8 * g;
            const float4 v0 = *reinterpret_cast<const float4*>(A + rE * D + c0);
            const float4 v1 = *reinterpret_cast<const float4*>(A + rE * D + c0 + 4);
            float e[8] = {v0.x, v0.y, v0.z, v0.w, v1.x, v1.y, v1.z, v1.w};
#pragma unroll
            for (int j = 0; j < 8; ++j)
                if (rE == c0 + j) e[j] += 1.0f;
            union { uint32_t u[4]; f16x8 v; } un;
            un.u[0] = pkrtz(e[0], e[1]);
            un.u[1] = pkrtz(e[2], e[3]);
            un.u[2] = pkrtz(e[4], e[5]);
            un.u[3] = pkrtz(e[6], e[7]);
            af[t][kh] = un.v;
        }
    }
    // "+v" pins: keep af loop-resident in arch VGPRs (R10: "+a" regressed).
#pragma unroll
    for (int t = 0; t < 4; ++t)
#pragma unroll
        for (int kh = 0; kh < 2; ++kh)
            asm volatile("" : "+v"(af[t][kh]));

    // r and x0 in the need-layout (dbase is a multiple of 4 -> f32x4 loads).
    f32x4 rl[4], x[4];
#pragma unroll
    for (int t = 0; t < 4; ++t) {
        rl[t] = *reinterpret_cast<const f32x4*>(r + dbase[t]);
        x[t]  = *reinterpret_cast<const f32x4*>(x0 + (b0 + p) * D + dbase[t]);
    }

    const float dt = tgrid[1] - tgrid[0];
    const float h2 = 0.5f * dt;
    const float h6 = dt * (1.0f / 6.0f);
    float* const outp = out + (size_t)b0 * NT * D;

    STORE_WRITE();                             // stage t=0 (x0); flushed in ts=1

    f32x4 s[4], xst[4], k[4];

    for (int ts = 1; ts < NT; ++ts) {
        FEVAL(x, k);                                   // k1 (no DS ops)
        STORE_FLUSH(ts - 1);                           // prev step, drain free
#pragma unroll
        for (int t = 0; t < 4; ++t) {
            s[t]   = x[t] + vsplat(h6) * k[t];
            xst[t] = x[t] + vsplat(h2) * k[t];
        }
        FEVAL(xst, k);                                 // k2
#pragma unroll
        for (int t = 0; t < 4; ++t) {
            s[t]   = s[t] + vsplat(2.0f * h6) * k[t];
            xst[t] = x[t] + vsplat(h2) * k[t];
        }
        FEVAL(xst, k);                                 // k3
#pragma unroll
        for (int t = 0; t < 4; ++t) {
            s[t]   = s[t] + vsplat(2.0f * h6) * k[t];
            xst[t] = x[t] + vsplat(dt) * k[t];
        }
        FEVAL(xst, k);                                 // k4
#pragma unroll
        for (int t = 0; t < 4; ++t)
            x[t] = s[t] + vsplat(h6) * k[t];

        STORE_WRITE();                                 // stage step ts
    }
    STORE_FLUSH(NT - 1);                               // final flush
}

extern "C" void kernel_launch(void* const* d_in, const int* in_sizes, int n_in,
                              void* d_out, int out_size, void* d_ws, size_t ws_size,
                              hipStream_t stream) {
    const float* x0    = (const float*)d_in[0];
    const float* r     = (const float*)d_in[1];
    const float* A     = (const float*)d_in[2];
    const float* tgrid = (const float*)d_in[3];
    float* out         = (float*)d_out;

    const int batch = in_sizes[0] / D;          // 2048
    dim3 grid(batch / BW);                      // 128 one-wave blocks
    dim3 block(64);

    glv_rk4_mfma<<<grid, block, 0, stream>>>(x0, r, A, tgrid, out);
}